// Round 1
// baseline (346.005 us; speedup 1.0000x reference)
//
#include <hip/hip_runtime.h>
#include <math.h>

// Problem constants (reference: B=4, S=4096, H=2048, E=64, K=8)
#define HDIM 2048
#define NEXP 64
#define TOPK 8
#define SLEN 4096
#define NBATCH 4
// Output layout (flat, float32):
//   [0, 131072)        topk_idx as float
//   [131072, 262144)   topk_w
//   [262144]           aux_seq_loss
//   [262145, 262209)   expert_load as float
#define OFF_W   131072
#define OFF_LOSS 262144
#define OFF_LOAD 262145

// ---------------------------------------------------------------------------
// Kernel 1: transpose W [E][H] -> Wt [H][E] so GEMM can s_load contiguous
// per-k expert rows.
__global__ __launch_bounds__(256) void transpose_w(const float* __restrict__ W,
                                                   float* __restrict__ Wt) {
  int idx = blockIdx.x * 256 + threadIdx.x;   // 0 .. 131071
  int e = idx >> 11;                          // / 2048
  int k = idx & 2047;
  Wt[k * NEXP + e] = W[idx];                  // read coalesced, write scattered (512 KB, ~us)
}

// ---------------------------------------------------------------------------
// Kernel 2: fused logits GEMM + sigmoid + top-8 + per-block load/P stats.
// grid 256, block 512 (8 waves). Block handles 64 tokens x all 64 experts.
// Wave w: experts [8w, 8w+8); lane = local token.
__global__ __launch_bounds__(512) void gate_main(
    const float* __restrict__ x,     // [16384][2048]
    const float* __restrict__ Wt,    // [2048][64]
    const float* __restrict__ bias,  // [64]
    float* __restrict__ out,
    float* __restrict__ Pacc,        // [4][64] global accum (zeroed)
    float* __restrict__ Cacc) {      // [4][64] global accum (zeroed)
  __shared__ float xs[64][64];       // [k][tok], XOR-swizzled columns
  __shared__ float lg[64][65];       // logits [tok][e], +1 pad
  __shared__ float ssum_sh[64];
  __shared__ unsigned cnt_sh[64];

  const int tid = threadIdx.x;
  const int lane = tid & 63;
  const int wv = __builtin_amdgcn_readfirstlane(tid >> 6);  // force SGPR
  const int blk = blockIdx.x;
  const int tok0 = blk << 6;

  if (tid < 64) cnt_sh[tid] = 0u;

  float acc[8] = {0.f, 0.f, 0.f, 0.f, 0.f, 0.f, 0.f, 0.f};

  // --- staging mapping: thread loads one float4 from two token rows/tile ---
  const int kc = (tid & 15) << 2;   // k offset within tile: 0,4,...,60
  const int tr = tid >> 4;          // token row 0..31 (and tr+32)
  const float* xb = x + (size_t)tok0 * HDIM;

  float4 a0, a1;
  {
    a0 = *(const float4*)(xb + (size_t)tr * HDIM + kc);
    a1 = *(const float4*)(xb + (size_t)(tr + 32) * HDIM + kc);
  }

  for (int kt = 0; kt < 32; ++kt) {
    const int k0 = kt << 6;
    __syncthreads();  // previous tile's compute done; xs free
    {
      const float* f0 = (const float*)&a0;
      const float* f1 = (const float*)&a1;
#pragma unroll
      for (int i = 0; i < 4; ++i) {
        int k = kc + i;
        int c = (k >> 1) & 31;             // XOR swizzle: <=2-way banks both ways
        xs[k][tr ^ c] = f0[i];
        xs[k][(tr + 32) ^ c] = f1[i];
      }
    }
    __syncthreads();  // xs ready
    // issue next tile's global loads before compute (reg double-buffer)
    if (kt + 1 < 32) {
      const int kn = k0 + 64 + kc;
      a0 = *(const float4*)(xb + (size_t)tr * HDIM + kn);
      a1 = *(const float4*)(xb + (size_t)(tr + 32) * HDIM + kn);
    }
    // compute: 64 k-steps, 8 fmac each; W via wave-uniform (scalar) loads
    const float* wbase = Wt + ((size_t)k0 << 6) + (wv << 3);
#pragma unroll 8
    for (int kk = 0; kk < 64; ++kk) {
      float xv = xs[kk][lane ^ ((kk >> 1) & 31)];
      const float* wr = wbase + (kk << 6);
#pragma unroll
      for (int j = 0; j < 8; ++j) acc[j] = fmaf(xv, wr[j], acc[j]);
    }
  }

  // --- dump logits to LDS ---
#pragma unroll
  for (int j = 0; j < 8; ++j) lg[lane][(wv << 3) + j] = acc[j];
  __syncthreads();

  // --- epilogue: wave 0, lane = local token ---
  if (tid < 64) {
    const int token = tok0 + lane;
    // full score sum (denominator of P normalization)
    float ssum = 0.f;
#pragma unroll 8
    for (int e = 0; e < NEXP; ++e) {
      float l = lg[lane][e];
      ssum += 1.f / (1.f + expf(-l));
    }
    ssum_sh[lane] = ssum;

    // top-8 by biased logit; ascending scan with strict '>' == lax.top_k
    // tie-break (lowest index first)
    unsigned long long chosen = 0ull;
    int is8[TOPK];
    float sc8[TOPK];
    float selsum = 0.f;
#pragma unroll
    for (int j = 0; j < TOPK; ++j) {
      float best = -1e30f;
      int bi = 0;
      for (int e = 0; e < NEXP; ++e) {
        if (!((chosen >> e) & 1ull)) {
          float bl = lg[lane][e] + bias[e];
          if (bl > best) { best = bl; bi = e; }
        }
      }
      chosen |= (1ull << bi);
      is8[j] = bi;
      float sc = 1.f / (1.f + expf(-lg[lane][bi]));
      sc8[j] = sc;
      selsum += sc;
    }
    float inv = 1.f / (selsum + 1e-10f);

    float* oi = out + (size_t)token * TOPK;
    float* ow = out + OFF_W + (size_t)token * TOPK;
#pragma unroll
    for (int j = 0; j < TOPK; ++j) {
      oi[j] = (float)is8[j];
      ow[j] = sc8[j] * inv;
    }
#pragma unroll
    for (int j = 0; j < TOPK; ++j) atomicAdd(&cnt_sh[is8[j]], 1u);

    // P accumulation: lane = expert, sum normalized score over block tokens
    float p = 0.f;
    for (int t = 0; t < 64; ++t) {
      float l = lg[t][lane];
      float sc = 1.f / (1.f + expf(-l));
      p += sc / (ssum_sh[t] + 1e-10f);
    }
    const int b = blk >> 6;  // 64 blocks per batch (64*64 = 4096 tokens)
    atomicAdd(&Pacc[(b << 6) + lane], p);
    atomicAdd(&Cacc[(b << 6) + lane], (float)cnt_sh[lane]);
  }
}

// ---------------------------------------------------------------------------
// Kernel 3: loss scalar + expert_load from the [4][64] tables.
__global__ __launch_bounds__(64) void finalize(const float* __restrict__ Pacc,
                                               const float* __restrict__ Cacc,
                                               float* __restrict__ out) {
  int e = threadIdx.x;  // 0..63
  float load = 0.f, part = 0.f;
#pragma unroll
  for (int b = 0; b < NBATCH; ++b) {
    float c = Cacc[(b << 6) + e];
    float p = Pacc[(b << 6) + e];
    load += c;
    // f_i = c/(K*S); P_i = p/S
    part += (c * (1.f / (TOPK * (float)SLEN))) * (p * (1.f / (float)SLEN));
  }
  out[OFF_LOAD + e] = load;
#pragma unroll
  for (int off = 32; off; off >>= 1) part += __shfl_down(part, off);
  if (e == 0) out[OFF_LOSS] = 0.01f * part * (1.f / (float)NBATCH);
}

// ---------------------------------------------------------------------------
extern "C" void kernel_launch(void* const* d_in, const int* in_sizes, int n_in,
                              void* d_out, int out_size, void* d_ws, size_t ws_size,
                              hipStream_t stream) {
  const float* x = (const float*)d_in[0];     // [4,4096,2048]
  const float* W = (const float*)d_in[1];     // [64,2048]
  const float* bias = (const float*)d_in[2];  // [64]
  float* out = (float*)d_out;

  // ws layout: Wt 512 KB | P 1 KB | C 1 KB
  float* Wt = (float*)d_ws;
  float* P = (float*)((char*)d_ws + 2048 * 64 * sizeof(float));
  float* C = P + NBATCH * NEXP;

  hipMemsetAsync(P, 0, 2 * NBATCH * NEXP * sizeof(float), stream);
  transpose_w<<<512, 256, 0, stream>>>(W, Wt);
  gate_main<<<256, 512, 0, stream>>>(x, Wt, bias, out, P, C);
  finalize<<<1, 64, 0, stream>>>(P, C, out);
}

// Round 2
// 280.809 us; speedup vs baseline: 1.2322x; 1.2322x over previous
//
#include <hip/hip_runtime.h>
#include <math.h>

// Problem: B=4, S=4096, H=2048, E=64, K=8; T = 16384 tokens.
#define HDIM 2048
#define TTOK 16384
#define NEXP 64
#define TOPK 8
#define SLEN 4096
#define NBATCH 4
#define KSPLIT 4
#define KRANGE 512            // HDIM / KSPLIT
#define PARTSZ 1048576        // NEXP * TTOK floats per k-split partial

// Output layout (flat, float32):
#define OFF_W    131072
#define OFF_LOSS 262144
#define OFF_LOAD 262145

// ws layout (float offsets):
//   [0, 131072)                 Wt [2048][64]
//   [262144, 262144+4*PARTSZ)   partial logits, 4 x [64 e][16384 tok]
//   then Pacc[4][64], Cacc[4][64]
#define WS_PART 262144
#define WS_PACC (WS_PART + 4 * PARTSZ)
#define WS_CACC (WS_PACC + NBATCH * NEXP)

// ---------------------------------------------------------------------------
// Kernel 1: LDS-tiled transpose W [64][2048] -> Wt [2048][64].
// Coalesced global loads AND stores; grid 32 x 256.
__global__ __launch_bounds__(256) void transpose_w(const float* __restrict__ W,
                                                   float* __restrict__ Wt) {
  __shared__ float tile[64][65];
  const int tid = threadIdx.x;
  const int k0 = blockIdx.x * 64;
  {
    const int kc = (tid & 15) << 2;  // 0,4,...,60
    const int er = tid >> 4;         // 0..15
#pragma unroll
    for (int i = 0; i < 4; ++i) {
      int e = er + i * 16;
      float4 v = *(const float4*)(W + (size_t)e * HDIM + k0 + kc);
      tile[e][kc + 0] = v.x; tile[e][kc + 1] = v.y;
      tile[e][kc + 2] = v.z; tile[e][kc + 3] = v.w;
    }
  }
  __syncthreads();
  {
    const int e4 = (tid & 15) << 2;
    const int kr = tid >> 4;
#pragma unroll
    for (int i = 0; i < 4; ++i) {
      int k = kr + i * 16;
      float4 v;
      v.x = tile[e4 + 0][k]; v.y = tile[e4 + 1][k];
      v.z = tile[e4 + 2][k]; v.w = tile[e4 + 3][k];
      *(float4*)(Wt + (size_t)(k0 + k) * NEXP + e4) = v;
    }
  }
}

// ---------------------------------------------------------------------------
// Kernel 2: logits GEMM, K-split 4. grid 1024 = 256 token-groups x 4 k-ranges.
// Block 512 thr = 8 waves; wave w -> experts [8w,8w+8); lane = local token.
// x staged in LDS [tok][k] rows with 16B-granule XOR swizzle; read b128.
// W via wave-uniform (scalar) loads from Wt [k][e].
__global__ __launch_bounds__(512, 8) void gate_gemm(
    const float* __restrict__ x,   // [16384][2048]
    const float* __restrict__ Wt,  // [2048][64]
    float* __restrict__ part) {    // 4 x [64][16384]
  __shared__ float xs[2][64][64];  // 32 KB

  const int tid = threadIdx.x;
  const int lane = tid & 63;
  const int wv = __builtin_amdgcn_readfirstlane(tid >> 6);
  const int kh = blockIdx.x & 3;
  const int tg = blockIdx.x >> 2;
  const int tok0 = tg << 6;
  const int kbase = kh * KRANGE;

  float acc[8] = {0.f, 0.f, 0.f, 0.f, 0.f, 0.f, 0.f, 0.f};

  // staging map: thread -> token row st, granules sg and sg+8 (16B each)
  const int st = tid >> 3;                 // 0..63
  const int sg = tid & 7;                  // 0..7
  const int swz = st & 15;
  const float* xrow = x + (size_t)(tok0 + st) * HDIM + kbase;

  float4 a0 = *(const float4*)(xrow + (sg << 2));
  float4 a1 = *(const float4*)(xrow + 32 + (sg << 2));

  const int rsw = lane & 15;
  for (int kt = 0; kt < 8; ++kt) {
    float(*xb)[64] = xs[kt & 1];
    *(float4*)&xb[st][(sg ^ swz) << 2] = a0;
    *(float4*)&xb[st][((sg + 8) ^ swz) << 2] = a1;
    __syncthreads();  // single barrier per tile (double buffer)
    if (kt + 1 < 8) {
      const float* nr = xrow + ((kt + 1) << 6);
      a0 = *(const float4*)(nr + (sg << 2));
      a1 = *(const float4*)(nr + 32 + (sg << 2));
    }
    const float* wbase = Wt + (size_t)(kbase + (kt << 6)) * NEXP + (wv << 3);
#pragma unroll
    for (int g = 0; g < 16; ++g) {
      float4 xv4 = *(const float4*)&xb[lane][(g ^ rsw) << 2];
      const float xv[4] = {xv4.x, xv4.y, xv4.z, xv4.w};
#pragma unroll
      for (int i = 0; i < 4; ++i) {
        const float* wr = wbase + (((g << 2) + i) << 6);  // wave-uniform -> s_load
#pragma unroll
        for (int j = 0; j < 8; ++j) acc[j] = fmaf(xv[i], wr[j], acc[j]);
      }
    }
  }

  // store partial logits, [e][tok] layout -> coalesced dword stores
  float* dst = part + (size_t)kh * PARTSZ + ((size_t)(wv << 3) << 14) + tok0 + lane;
#pragma unroll
  for (int j = 0; j < 8; ++j) dst[(size_t)j << 14] = acc[j];
}

// ---------------------------------------------------------------------------
// Kernel 3: epilogue. grid 64 x 256; thread = token. Combines 4 partials,
// sigmoid, top-8 (strict '>' ascending = lax.top_k tie-break), weights,
// per-block load counts and P-statistics.
__global__ __launch_bounds__(256) void gate_epilogue(
    const float* __restrict__ part, const float* __restrict__ bias,
    float* __restrict__ out, float* __restrict__ Pacc,
    float* __restrict__ Cacc) {
  __shared__ float psum[64];
  __shared__ unsigned csum[64];
  const int tid = threadIdx.x;
  const int t = blockIdx.x * 256 + tid;

  if (tid < 64) { psum[tid] = 0.f; csum[tid] = 0u; }
  __syncthreads();

  // biased logits in registers; running sigmoid sum
  float bl[64];
  float ssum = 0.f;
#pragma unroll
  for (int e = 0; e < NEXP; ++e) {
    const float* p = part + ((size_t)e << 14) + t;
    float l = p[0] + p[PARTSZ] + p[2 * PARTSZ] + p[3 * PARTSZ];
    ssum += 1.f / (1.f + expf(-l));
    bl[e] = l + bias[e];
  }

  // top-8
  unsigned long long chosen = 0ull;
  int i8[TOPK];
  float w8[TOPK];
  float wsum = 0.f;
#pragma unroll
  for (int j = 0; j < TOPK; ++j) {
    float best = -1e30f;
    int bi = 0;
    float braw = 0.f;
#pragma unroll
    for (int e = 0; e < NEXP; ++e) {
      bool ok = (((chosen >> e) & 1ull) == 0ull) && (bl[e] > best);
      if (ok) { best = bl[e]; bi = e; braw = bl[e] - bias[e]; }
    }
    chosen |= (1ull << bi);
    float sc = 1.f / (1.f + expf(-braw));
    i8[j] = bi;
    w8[j] = sc;
    wsum += sc;
  }
  float inv = 1.f / (wsum + 1e-10f);

  {
    float4 o;
    o.x = (float)i8[0]; o.y = (float)i8[1]; o.z = (float)i8[2]; o.w = (float)i8[3];
    *(float4*)(out + (size_t)t * TOPK) = o;
    o.x = (float)i8[4]; o.y = (float)i8[5]; o.z = (float)i8[6]; o.w = (float)i8[7];
    *(float4*)(out + (size_t)t * TOPK + 4) = o;
    o.x = w8[0] * inv; o.y = w8[1] * inv; o.z = w8[2] * inv; o.w = w8[3] * inv;
    *(float4*)(out + OFF_W + (size_t)t * TOPK) = o;
    o.x = w8[4] * inv; o.y = w8[5] * inv; o.z = w8[6] * inv; o.w = w8[7] * inv;
    *(float4*)(out + OFF_W + (size_t)t * TOPK + 4) = o;
  }

  // load counts (random experts -> few-way LDS atomic collisions, cheap)
#pragma unroll
  for (int j = 0; j < TOPK; ++j) atomicAdd(&csum[i8[j]], 1u);

  // P statistic: wave-reduce normalized score per expert, lane0 adds to LDS
  float rinv = 1.f / (ssum + 1e-10f);
#pragma unroll
  for (int e = 0; e < NEXP; ++e) {
    float sc = 1.f / (1.f + expf(-(bl[e] - bias[e])));
    float v = sc * rinv;
#pragma unroll
    for (int off = 32; off; off >>= 1) v += __shfl_xor(v, off);
    if ((tid & 63) == 0) atomicAdd(&psum[e], v);
  }
  __syncthreads();

  if (tid < 64) {
    const int b = blockIdx.x >> 4;  // 16 blocks of 256 tokens per batch
    atomicAdd(&Pacc[(b << 6) + tid], psum[tid]);
    atomicAdd(&Cacc[(b << 6) + tid], (float)csum[tid]);
  }
}

// ---------------------------------------------------------------------------
// Kernel 4: loss scalar + expert_load from the [4][64] tables.
__global__ __launch_bounds__(64) void finalize(const float* __restrict__ Pacc,
                                               const float* __restrict__ Cacc,
                                               float* __restrict__ out) {
  int e = threadIdx.x;  // 0..63
  float load = 0.f, partl = 0.f;
#pragma unroll
  for (int b = 0; b < NBATCH; ++b) {
    float c = Cacc[(b << 6) + e];
    float p = Pacc[(b << 6) + e];
    load += c;
    partl += (c * (1.f / (TOPK * (float)SLEN))) * (p * (1.f / (float)SLEN));
  }
  out[OFF_LOAD + e] = load;
#pragma unroll
  for (int off = 32; off; off >>= 1) partl += __shfl_down(partl, off);
  if (e == 0) out[OFF_LOSS] = 0.01f * partl * (1.f / (float)NBATCH);
}

// ---------------------------------------------------------------------------
extern "C" void kernel_launch(void* const* d_in, const int* in_sizes, int n_in,
                              void* d_out, int out_size, void* d_ws, size_t ws_size,
                              hipStream_t stream) {
  const float* x = (const float*)d_in[0];     // [4,4096,2048]
  const float* W = (const float*)d_in[1];     // [64,2048]
  const float* bias = (const float*)d_in[2];  // [64]
  float* out = (float*)d_out;

  float* ws = (float*)d_ws;
  float* Wt = ws;
  float* part = ws + WS_PART;
  float* Pacc = ws + WS_PACC;
  float* Cacc = ws + WS_CACC;

  hipMemsetAsync(Pacc, 0, 2 * NBATCH * NEXP * sizeof(float), stream);
  transpose_w<<<32, 256, 0, stream>>>(W, Wt);
  gate_gemm<<<1024, 512, 0, stream>>>(x, Wt, part);
  gate_epilogue<<<64, 256, 0, stream>>>(part, bias, out, Pacc, Cacc);
  finalize<<<1, 64, 0, stream>>>(Pacc, Cacc, out);
}